// Round 2
// baseline (551.976 us; speedup 1.0000x reference)
//
#include <hip/hip_runtime.h>

#define NROWS 65536
#define DIM   64
#define NCODE 1024
#define PARTS 4                    // K-split: 4 waves share a row group
#define KPT   (NCODE / PARTS)      // 256 codes per wave
#define RPB   64                   // rows per block (= lanes)
#define NTHR  (RPB * PARTS)        // 256 threads = 4 waves
#define NBLK  (NROWS / RPB)        // 1024 blocks -> 4 blocks/CU -> 16 waves/CU

// ---- pre-pass: ||e_k||^2 for all 1024 codes ----
__global__ __launch_bounds__(256) void vq_e2(const float* __restrict__ e,
                                             float* __restrict__ e2) {
  const int k = blockIdx.x * 256 + threadIdx.x;
  const float4* p = reinterpret_cast<const float4*>(e + (size_t)k * DIM);
  float s = 0.f;
  #pragma unroll
  for (int i = 0; i < DIM / 4; ++i) {
    float4 v = p[i];
    s = fmaf(v.x, v.x, fmaf(v.y, v.y, fmaf(v.z, v.z, fmaf(v.w, v.w, s))));
  }
  e2[k] = s;
}

// ---- main: one lane = one row; wave p scans codes [p*256, p*256+256).
// k is wave-uniform -> e reads scalarize (s_load) / broadcast; no LDS in the
// hot loop, no bank conflicts, VALU does only FMAs + tiny epilogue.
__global__ __launch_bounds__(NTHR) void vq_main(
    const float* __restrict__ x,
    const float* __restrict__ e,
    const float* __restrict__ e2,
    float* __restrict__ out,
    float* __restrict__ partial)
{
  __shared__ float bestL[PARTS][RPB];
  __shared__ int   kL[PARTS][RPB];
  __shared__ int   kFin[RPB];

  const int t    = threadIdx.x;
  const int lane = t & 63;
  const int part = t >> 6;
  const size_t row = (size_t)blockIdx.x * RPB + lane;

  // x row -> 64 VGPRs
  float xr[DIM];
  {
    const float4* xg = reinterpret_cast<const float4*>(x + row * DIM);
    #pragma unroll
    for (int i = 0; i < DIM / 4; ++i) {
      float4 v = xg[i];
      xr[4*i+0] = v.x; xr[4*i+1] = v.y; xr[4*i+2] = v.z; xr[4*i+3] = v.w;
    }
  }
  float x2 = 0.f;
  #pragma unroll
  for (int j = 0; j < DIM; ++j) x2 = fmaf(xr[j], xr[j], x2);

  const int kbase = part * KPT;
  const float* __restrict__ ep  = e  + (size_t)kbase * DIM;
  const float* __restrict__ e2p = e2 + kbase;

  float best = 3.4e38f;
  int   bestk = kbase;

  #pragma unroll 2
  for (int k = 0; k < KPT; ++k) {
    const float* __restrict__ ek = ep + k * DIM;   // wave-uniform address
    float a0 = 0.f, a1 = 0.f, a2 = 0.f, a3 = 0.f;
    #pragma unroll
    for (int i = 0; i < DIM / 4; ++i) {
      a0 = fmaf(xr[4*i+0], ek[4*i+0], a0);
      a1 = fmaf(xr[4*i+1], ek[4*i+1], a1);
      a2 = fmaf(xr[4*i+2], ek[4*i+2], a2);
      a3 = fmaf(xr[4*i+3], ek[4*i+3], a3);
    }
    float d = (x2 - 2.0f * ((a0 + a1) + (a2 + a3))) + e2p[k];
    if (d < best) { best = d; bestk = kbase + k; }
  }

  bestL[part][lane] = best;
  kL[part][lane]    = bestk;
  __syncthreads();

  float rowbest = 0.f;
  if (part == 0) {
    float b = bestL[0][lane]; int bk = kL[0][lane];
    #pragma unroll
    for (int p = 1; p < PARTS; ++p) {           // ascending part order ->
      float d = bestL[p][lane];                 // strict < keeps lowest k on tie
      int  dk = kL[p][lane];
      if (d < b) { b = d; bk = dk; }
    }
    kFin[lane] = bk;
    rowbest = b;
  }
  __syncthreads();

  // gather-write: each part writes its 16-float segment of the row
  {
    const int bk = kFin[lane];
    const float4* src = reinterpret_cast<const float4*>(
        e + (size_t)bk * DIM + part * 16);
    float4* dst = reinterpret_cast<float4*>(out + row * DIM + part * 16);
    #pragma unroll
    for (int i = 0; i < 4; ++i) dst[i] = src[i];
  }

  // per-block loss partial: wave 0 holds 64 row-bests; deterministic xor tree
  if (part == 0) {
    float v = rowbest;
    #pragma unroll
    for (int o = 32; o > 0; o >>= 1) v += __shfl_xor(v, o, 64);
    if (lane == 0) partial[blockIdx.x] = v;
  }
}

__global__ __launch_bounds__(1024) void vq_fin(const float* __restrict__ partial,
                                               float* __restrict__ loss)
{
  __shared__ float red[1024];
  const int t = threadIdx.x;
  red[t] = partial[t];
  __syncthreads();
  #pragma unroll
  for (int w = 512; w > 0; w >>= 1) {
    if (t < w) red[t] += red[t + w];
    __syncthreads();
  }
  if (t == 0)
    loss[0] = red[0] * (1.25f / (float)((size_t)NROWS * DIM));
}

extern "C" void kernel_launch(void* const* d_in, const int* in_sizes, int n_in,
                              void* d_out, int out_size, void* d_ws, size_t ws_size,
                              hipStream_t stream) {
  const float* x = (const float*)d_in[0];   // [65536, 64]
  const float* e = (const float*)d_in[1];   // [1024, 64]
  float* out = (float*)d_out;               // quantized_st [65536*64] + loss [1]
  float* e2      = (float*)d_ws;            // 1024 floats
  float* partial = (float*)d_ws + NCODE;    // 1024 floats

  vq_e2 <<<NCODE / 256, 256, 0, stream>>>(e, e2);
  vq_main<<<NBLK, NTHR, 0, stream>>>(x, e, e2, out, partial);
  vq_fin <<<1, NBLK, 0, stream>>>(partial, out + (size_t)NROWS * DIM);
}

// Round 3
// 119.093 us; speedup vs baseline: 4.6348x; 4.6348x over previous
//
#include <hip/hip_runtime.h>

#define DIM    64
#define NROWS  65536
#define NCODE  1024
#define NTHR   256                 // 4 waves
#define NBLK   (NROWS / 64)        // 1024 blocks, 64 rows each

// LDS float offsets (total 20480 floats = 80 KB -> 2 blocks/CU)
#define XT     0                   // xT[k][r] : [64][64]
#define TILE0  4096                // wave w's eT tile at TILE0 + w*4096 : eT[k][c] [64][64]
// pre-phase alias:  x2L[64]            at TILE0
// post-phase alias: bestW[4][64] float at TILE0, kW[4][64] int at TILE0+256,
//                   kFin[64] int       at TILE0+512

// ---- pre-pass: transpose e -> eTg[64][1024] and e2g[k] = ||e_k||^2 ----
__global__ __launch_bounds__(256) void vq_pre(const float* __restrict__ e,
                                              float* __restrict__ eTg,
                                              float* __restrict__ e2g) {
  const int c = blockIdx.x * 256 + threadIdx.x;
  float v[DIM];
  const float4* p = reinterpret_cast<const float4*>(e + (size_t)c * DIM);
  float s = 0.f;
  #pragma unroll
  for (int i = 0; i < DIM / 4; ++i) {
    float4 q = p[i];
    v[4*i+0] = q.x; v[4*i+1] = q.y; v[4*i+2] = q.z; v[4*i+3] = q.w;
    s = fmaf(q.x, q.x, fmaf(q.y, q.y, fmaf(q.z, q.z, fmaf(q.w, q.w, s))));
  }
  e2g[c] = s;
  #pragma unroll
  for (int d = 0; d < DIM; ++d) eTg[d * NCODE + c] = v[d];  // coalesced in c
}

// ---- main: lane computes an 8-row x 8-code register tile ----
// wave w owns codes [w*256, (w+1)*256) in 4 chunks of 64; all 4 waves share
// the block's 64 rows. Per k-step: 2 ds_read_b128 (xT) + 2 (eT) feed 64 FMAs.
__global__ __launch_bounds__(NTHR, 2) void vq_main(
    const float* __restrict__ x,
    const float* __restrict__ e,
    const float* __restrict__ eTg,
    const float* __restrict__ e2g,
    float* __restrict__ out,
    float* __restrict__ partial)
{
  __shared__ float lds[20480];
  int* ldsI = (int*)lds;

  const int t    = threadIdx.x;
  const int lane = t & 63;
  const int w    = t >> 6;
  const int lr   = lane >> 3;     // row group: rows lr*8..lr*8+7
  const int lc   = lane & 7;      // code group: codes cb + lc*8..+7
  const int B0   = blockIdx.x * 64;

  // ---- stage xT (transposed) + per-row ||x||^2 ----
  {
    const int row = t >> 2, seg = t & 3;
    const float4* xg = reinterpret_cast<const float4*>(
        x + (size_t)(B0 + row) * DIM + seg * 16);
    float4 a0 = xg[0], a1 = xg[1], a2 = xg[2], a3 = xg[3];
    float tmp[16] = {a0.x,a0.y,a0.z,a0.w, a1.x,a1.y,a1.z,a1.w,
                     a2.x,a2.y,a2.z,a2.w, a3.x,a3.y,a3.z,a3.w};
    float ps = 0.f;
    #pragma unroll
    for (int j = 0; j < 16; ++j) ps = fmaf(tmp[j], tmp[j], ps);
    ps += __shfl_xor(ps, 1, 64);      // threads 4r..4r+3 hold row r partials
    ps += __shfl_xor(ps, 2, 64);
    #pragma unroll
    for (int j = 0; j < 16; ++j) lds[XT + (seg * 16 + j) * 64 + row] = tmp[j];
    if (seg == 0) lds[TILE0 + row] = ps;   // x2L (aliased, read before tiles)
  }
  __syncthreads();

  float x2r[8];
  #pragma unroll
  for (int rr = 0; rr < 8; ++rr) x2r[rr] = lds[TILE0 + lr * 8 + rr];
  __syncthreads();   // everyone has x2 before wave 0 overwrites TILE0

  float* tile = &lds[TILE0 + w * 4096];
  float bestd[8];
  int   bestk[8];
  #pragma unroll
  for (int rr = 0; rr < 8; ++rr) { bestd[rr] = 3.4e38f; bestk[rr] = 0; }

  const int cb0 = w * 256;
  for (int cc = 0; cc < 4; ++cc) {
    const int cb = cb0 + cc * 64;

    // stage eT chunk [64 k][64 codes] (wave-private, no block barrier)
    {
      const int krow = lane >> 4, col4 = (lane & 15) * 4;
      const float* src = eTg + (size_t)krow * NCODE + cb + col4;
      float* dst = tile + lane * 4;
      #pragma unroll
      for (int i = 0; i < 16; ++i) {
        float4 v = *reinterpret_cast<const float4*>(src + (size_t)(i * 4) * NCODE);
        *reinterpret_cast<float4*>(dst + i * 256) = v;
      }
    }
    float e2r[8];
    {
      float4 p = *reinterpret_cast<const float4*>(e2g + cb + lc * 8);
      float4 q = *reinterpret_cast<const float4*>(e2g + cb + lc * 8 + 4);
      e2r[0]=p.x; e2r[1]=p.y; e2r[2]=p.z; e2r[3]=p.w;
      e2r[4]=q.x; e2r[5]=q.y; e2r[6]=q.z; e2r[7]=q.w;
    }

    float acc[8][8];
    #pragma unroll
    for (int rr = 0; rr < 8; ++rr)
      #pragma unroll
      for (int j = 0; j < 8; ++j) acc[rr][j] = 0.f;

    const float* xp = &lds[XT + lr * 8];
    const float* ep = tile + lc * 8;
    #pragma unroll 4
    for (int k = 0; k < 64; ++k) {
      float4 xa = *reinterpret_cast<const float4*>(xp + k * 64);
      float4 xb = *reinterpret_cast<const float4*>(xp + k * 64 + 4);
      float4 ea = *reinterpret_cast<const float4*>(ep + k * 64);
      float4 eb = *reinterpret_cast<const float4*>(ep + k * 64 + 4);
      float xf[8] = {xa.x,xa.y,xa.z,xa.w, xb.x,xb.y,xb.z,xb.w};
      float ef[8] = {ea.x,ea.y,ea.z,ea.w, eb.x,eb.y,eb.z,eb.w};
      #pragma unroll
      for (int rr = 0; rr < 8; ++rr)
        #pragma unroll
        for (int j = 0; j < 8; ++j)
          acc[rr][j] = fmaf(xf[rr], ef[j], acc[rr][j]);
    }

    // fold chunk into running argmin (ascending k, strict-less = first-index ties)
    #pragma unroll
    for (int rr = 0; rr < 8; ++rr) {
      #pragma unroll
      for (int j = 0; j < 8; ++j) {
        float dd = fmaf(-2.f, acc[rr][j], x2r[rr]) + e2r[j];  // ref rounding
        int   kv = cb + lc * 8 + j;
        if (dd < bestd[rr]) { bestd[rr] = dd; bestk[rr] = kv; }
      }
    }
  }

  // ---- intra-wave merge across the 8 code groups (lexicographic on ties) ----
  #pragma unroll
  for (int off = 1; off <= 4; off <<= 1) {
    #pragma unroll
    for (int rr = 0; rr < 8; ++rr) {
      float dp = __shfl_xor(bestd[rr], off, 64);
      int   kp = __shfl_xor(bestk[rr], off, 64);
      bool take = (dp < bestd[rr]) || (dp == bestd[rr] && kp < bestk[rr]);
      if (take) { bestd[rr] = dp; bestk[rr] = kp; }
    }
  }

  __syncthreads();   // all compute done; eT space reusable
  if (lc == 0) {
    #pragma unroll
    for (int rr = 0; rr < 8; ++rr) {
      lds [TILE0 +       w * 64 + lr * 8 + rr] = bestd[rr];
      ldsI[TILE0 + 256 + w * 64 + lr * 8 + rr] = bestk[rr];
    }
  }
  __syncthreads();

  // ---- cross-wave merge (waves hold ascending code ranges) + loss ----
  if (t < 64) {
    float b  = lds [TILE0 + t];
    int   bk = ldsI[TILE0 + 256 + t];
    #pragma unroll
    for (int ww = 1; ww < 4; ++ww) {
      float d2 = lds [TILE0 +       ww * 64 + t];
      int   k2 = ldsI[TILE0 + 256 + ww * 64 + t];
      if (d2 < b) { b = d2; bk = k2; }
    }
    ldsI[TILE0 + 512 + t] = bk;
    float s = b;
    #pragma unroll
    for (int off = 32; off > 0; off >>= 1) s += __shfl_xor(s, off, 64);
    if (t == 0) partial[blockIdx.x] = s;
  }
  __syncthreads();

  // ---- cooperative gather-write of quantized rows ----
  {
    const int row = t >> 2, seg = t & 3;
    const int bk = ldsI[TILE0 + 512 + row];
    const float4* src = reinterpret_cast<const float4*>(
        e + (size_t)bk * DIM + seg * 16);
    float4* dst = reinterpret_cast<float4*>(
        out + (size_t)(B0 + row) * DIM + seg * 16);
    #pragma unroll
    for (int i = 0; i < 4; ++i) dst[i] = src[i];
  }
}

__global__ __launch_bounds__(1024) void vq_fin(const float* __restrict__ partial,
                                               float* __restrict__ loss)
{
  __shared__ float red[1024];
  const int t = threadIdx.x;
  red[t] = partial[t];
  __syncthreads();
  #pragma unroll
  for (int s = 512; s > 0; s >>= 1) {
    if (t < s) red[t] += red[t + s];
    __syncthreads();
  }
  if (t == 0)
    loss[0] = red[0] * (1.25f / (float)((size_t)NROWS * DIM));
}

extern "C" void kernel_launch(void* const* d_in, const int* in_sizes, int n_in,
                              void* d_out, int out_size, void* d_ws, size_t ws_size,
                              hipStream_t stream) {
  const float* x = (const float*)d_in[0];   // [65536, 64]
  const float* e = (const float*)d_in[1];   // [1024, 64]
  float* out = (float*)d_out;               // quantized_st [65536*64] + loss [1]

  float* eTg     = (float*)d_ws;                    // 65536 floats
  float* e2g     = (float*)d_ws + NCODE * DIM;      // 1024 floats
  float* partial = e2g + NCODE;                     // 1024 floats

  vq_pre <<<NCODE / 256, 256, 0, stream>>>(e, eTg, e2g);
  vq_main<<<NBLK, NTHR, 0, stream>>>(x, e, eTg, e2g, out, partial);
  vq_fin <<<1, NBLK, 0, stream>>>(partial, out + (size_t)NROWS * DIM);
}

// Round 4
// 69.253 us; speedup vs baseline: 7.9705x; 1.7197x over previous
//
#include <hip/hip_runtime.h>

#define DIM   64
#define NROWS 65536
#define NCODE 1024
#define NBLK  (NROWS / 64)      // 1024 blocks, 64 rows each

typedef float  f32x4  __attribute__((ext_vector_type(4)));
typedef __bf16 bf16x8 __attribute__((ext_vector_type(8)));

union U4B { uint4 u; bf16x8 b; };

// fp32 -> bf16 bits, round-to-nearest-even
__device__ __forceinline__ unsigned rne16(float f) {
  unsigned u = __float_as_uint(f);
  return (u + 0x7FFFu + ((u >> 16) & 1u)) >> 16;
}
__device__ __forceinline__ float up32(unsigned h) {
  return __uint_as_float(h << 16);
}
// x = hi + mid + lo (remainders exact by Sterbenz; ~24 mantissa bits total)
__device__ __forceinline__ void split3(float f, unsigned& h, unsigned& m, unsigned& l) {
  h = rne16(f);
  float r1 = f - up32(h);
  m = rne16(r1);
  float r2 = r1 - up32(m);
  l = rne16(r2);
}
__device__ __forceinline__ uint4 pack8(const unsigned* p) {
  return make_uint4(p[0] | (p[1] << 16), p[2] | (p[3] << 16),
                    p[4] | (p[5] << 16), p[6] | (p[7] << 16));
}

// ---- pre-pass: split e into bf16 triplets laid out as B-fragments, + e2/2 ----
// B-frag for (wct, kh, q): element (lane, i) = e_q[code = wct*16 + (lane&15)]
//                                             [k = kh*32 + (lane>>4)*8 + i]
__global__ __launch_bounds__(256) void vq_esplit(const float* __restrict__ e,
                                                 unsigned short* __restrict__ eB,
                                                 float* __restrict__ e2h) {
  const int c = blockIdx.x * 256 + threadIdx.x;   // code index, 1024 total
  const int ct16 = c >> 4, cl = c & 15;
  float s = 0.f;
  #pragma unroll
  for (int kh = 0; kh < 2; ++kh) {
    #pragma unroll
    for (int g = 0; g < 4; ++g) {
      const float* ep = e + (size_t)c * DIM + kh * 32 + g * 8;
      float4 v0 = *(const float4*)ep;
      float4 v1 = *(const float4*)(ep + 4);
      float f[8] = {v0.x, v0.y, v0.z, v0.w, v1.x, v1.y, v1.z, v1.w};
      unsigned hh[8], mm[8], ll[8];
      #pragma unroll
      for (int j = 0; j < 8; ++j) {
        split3(f[j], hh[j], mm[j], ll[j]);
        s = fmaf(f[j], f[j], s);
      }
      const size_t pos = (size_t)((g << 4) | cl) * 8;
      const size_t fb = (size_t)((ct16 * 2 + kh) * 3) << 9;
      *(uint4*)(eB + fb + (0 << 9) + pos) = pack8(hh);
      *(uint4*)(eB + fb + (1 << 9) + pos) = pack8(mm);
      *(uint4*)(eB + fb + (2 << 9) + pos) = pack8(ll);
    }
  }
  e2h[c] = 0.5f * s;
}

#define VQ_STEP(CT, BUF, E2L)                                                        \
  {                                                                                  \
    U4B ub;                                                                          \
    bf16x8 bb[6];                                                                    \
    _Pragma("unroll")                                                                \
    for (int q6 = 0; q6 < 6; ++q6) { ub.u = BUF[q6]; bb[q6] = ub.b; }                \
    const int kk0 = w * 256 + (CT) * 16 + col;                                       \
    _Pragma("unroll")                                                                \
    for (int rt = 0; rt < 4; ++rt) {                                                 \
      f32x4 c = {0.f, 0.f, 0.f, 0.f};                                                \
      c = __builtin_amdgcn_mfma_f32_16x16x32_bf16(a[rt][0][0], bb[0], c, 0, 0, 0);   \
      c = __builtin_amdgcn_mfma_f32_16x16x32_bf16(a[rt][0][0], bb[1], c, 0, 0, 0);   \
      c = __builtin_amdgcn_mfma_f32_16x16x32_bf16(a[rt][0][1], bb[0], c, 0, 0, 0);   \
      c = __builtin_amdgcn_mfma_f32_16x16x32_bf16(a[rt][0][0], bb[2], c, 0, 0, 0);   \
      c = __builtin_amdgcn_mfma_f32_16x16x32_bf16(a[rt][0][2], bb[0], c, 0, 0, 0);   \
      c = __builtin_amdgcn_mfma_f32_16x16x32_bf16(a[rt][0][1], bb[1], c, 0, 0, 0);   \
      c = __builtin_amdgcn_mfma_f32_16x16x32_bf16(a[rt][1][0], bb[3], c, 0, 0, 0);   \
      c = __builtin_amdgcn_mfma_f32_16x16x32_bf16(a[rt][1][0], bb[4], c, 0, 0, 0);   \
      c = __builtin_amdgcn_mfma_f32_16x16x32_bf16(a[rt][1][1], bb[3], c, 0, 0, 0);   \
      c = __builtin_amdgcn_mfma_f32_16x16x32_bf16(a[rt][1][0], bb[5], c, 0, 0, 0);   \
      c = __builtin_amdgcn_mfma_f32_16x16x32_bf16(a[rt][1][2], bb[3], c, 0, 0, 0);   \
      c = __builtin_amdgcn_mfma_f32_16x16x32_bf16(a[rt][1][1], bb[4], c, 0, 0, 0);   \
      _Pragma("unroll")                                                              \
      for (int r = 0; r < 4; ++r) {                                                  \
        float sc = c[r] - (E2L);                                                     \
        if (sc > bestS[rt][r]) { bestS[rt][r] = sc; bestK[rt][r] = kk0; }            \
      }                                                                              \
    }                                                                                \
  }

// ---- main: 64 rows/block, 4 waves; wave w scans codes [w*256, w*256+256) ----
__global__ __launch_bounds__(256, 2) void vq_main(
    const float* __restrict__ x,
    const float* __restrict__ e,
    const unsigned short* __restrict__ eB,
    const float* __restrict__ e2h,
    float* __restrict__ out,
    float* __restrict__ partial)
{
  __shared__ float bestL[256];
  __shared__ int   kL[256];
  __shared__ int   kFin[64];
  __shared__ float x2s;

  const int t   = threadIdx.x;
  const int l   = t & 63;
  const int w   = t >> 6;
  const int col = l & 15;
  const int g   = l >> 4;
  const int B0  = blockIdx.x * 64;

  // ---- load x directly in A-frag order; split to bf16 triplets in-reg ----
  bf16x8 a[4][2][3];     // [row-tile][k-half][h/m/l]
  float x2p = 0.f;
  #pragma unroll
  for (int rt = 0; rt < 4; ++rt) {
    #pragma unroll
    for (int kh = 0; kh < 2; ++kh) {
      const float* xp = x + (size_t)(B0 + rt * 16 + col) * DIM + kh * 32 + g * 8;
      float4 v0 = *(const float4*)xp;
      float4 v1 = *(const float4*)(xp + 4);
      float f[8] = {v0.x, v0.y, v0.z, v0.w, v1.x, v1.y, v1.z, v1.w};
      unsigned hh[8], mm[8], ll[8];
      #pragma unroll
      for (int j = 0; j < 8; ++j) {
        split3(f[j], hh[j], mm[j], ll[j]);
        x2p = fmaf(f[j], f[j], x2p);
      }
      U4B uh; uh.u = pack8(hh); a[rt][kh][0] = uh.b;
      U4B um; um.u = pack8(mm); a[rt][kh][1] = um.b;
      U4B ul; ul.u = pack8(ll); a[rt][kh][2] = ul.b;
    }
  }
  // block Sum(x^2): each wave covers all 64 rows x 64 dims exactly once
  #pragma unroll
  for (int off = 1; off < 64; off <<= 1) x2p += __shfl_xor(x2p, off, 64);
  if (t == 0) x2s = x2p;

  float bestS[4][4];
  int   bestK[4][4];
  #pragma unroll
  for (int rt = 0; rt < 4; ++rt)
    #pragma unroll
    for (int r = 0; r < 4; ++r) { bestS[rt][r] = -3.402823466e38f; bestK[rt][r] = 0; }

  const unsigned short* ebase = eB + (size_t)w * 16 * 3072;
  const float* e2w = e2h + w * 256 + col;

  uint4 bA[6], bB[6];
  float e2A, e2B;
  #pragma unroll
  for (int q6 = 0; q6 < 6; ++q6)
    bA[q6] = *(const uint4*)(ebase + ((size_t)q6 << 9) + l * 8);
  e2A = e2w[0];

  for (int ct = 0; ct < 16; ct += 2) {
    #pragma unroll
    for (int q6 = 0; q6 < 6; ++q6)
      bB[q6] = *(const uint4*)(ebase + (size_t)(ct + 1) * 3072 + ((size_t)q6 << 9) + l * 8);
    e2B = e2w[(ct + 1) * 16];
    VQ_STEP(ct, bA, e2A);
    const int ctn = (ct + 2 < 16) ? ct + 2 : 14;   // tail reload, harmless
    #pragma unroll
    for (int q6 = 0; q6 < 6; ++q6)
      bA[q6] = *(const uint4*)(ebase + (size_t)ctn * 3072 + ((size_t)q6 << 9) + l * 8);
    e2A = e2w[ctn * 16];
    VQ_STEP(ct + 1, bB, e2B);
  }

  // ---- intra-wave argmax(S') merge over the 16 code-columns ----
  #pragma unroll
  for (int off = 1; off <= 8; off <<= 1) {
    #pragma unroll
    for (int rt = 0; rt < 4; ++rt)
      #pragma unroll
      for (int r = 0; r < 4; ++r) {
        float sp = __shfl_xor(bestS[rt][r], off, 64);
        int   kp = __shfl_xor(bestK[rt][r], off, 64);
        if (sp > bestS[rt][r] || (sp == bestS[rt][r] && kp < bestK[rt][r])) {
          bestS[rt][r] = sp; bestK[rt][r] = kp;
        }
      }
  }
  if (col == 0) {
    #pragma unroll
    for (int rt = 0; rt < 4; ++rt)
      #pragma unroll
      for (int r = 0; r < 4; ++r) {
        const int row = rt * 16 + g * 4 + r;
        bestL[w * 64 + row] = bestS[rt][r];
        kL[w * 64 + row]    = bestK[rt][r];
      }
  }
  __syncthreads();

  // ---- cross-wave merge (ascending code ranges; strict > keeps lowest k) ----
  if (t < 64) {
    float s = bestL[t]; int k = kL[t];
    #pragma unroll
    for (int w2 = 1; w2 < 4; ++w2) {
      float s2 = bestL[w2 * 64 + t]; int k2 = kL[w2 * 64 + t];
      if (s2 > s) { s = s2; k = k2; }
    }
    kFin[t] = k;
    float rs = s;
    #pragma unroll
    for (int off = 1; off < 64; off <<= 1) rs += __shfl_xor(rs, off, 64);
    if (t == 0) partial[blockIdx.x] = fmaf(-2.f, rs, x2s);  // sum_d = x2 - 2*S'
  }
  __syncthreads();

  // ---- cooperative gather-write of quantized rows (exact fp32 e copy) ----
  {
    const int row = t >> 2, seg = t & 3;
    const int bk = kFin[row];
    const float4* src = (const float4*)(e + (size_t)bk * DIM + seg * 16);
    float4* dst = (float4*)(out + (size_t)(B0 + row) * DIM + seg * 16);
    #pragma unroll
    for (int i = 0; i < 4; ++i) dst[i] = src[i];
  }
}

__global__ __launch_bounds__(1024) void vq_fin(const float* __restrict__ partial,
                                               float* __restrict__ loss)
{
  __shared__ float red[1024];
  const int t = threadIdx.x;
  red[t] = partial[t];
  __syncthreads();
  #pragma unroll
  for (int s = 512; s > 0; s >>= 1) {
    if (t < s) red[t] += red[t + s];
    __syncthreads();
  }
  if (t == 0)
    loss[0] = red[0] * (1.25f / (float)((size_t)NROWS * DIM));
}

extern "C" void kernel_launch(void* const* d_in, const int* in_sizes, int n_in,
                              void* d_out, int out_size, void* d_ws, size_t ws_size,
                              hipStream_t stream) {
  const float* x = (const float*)d_in[0];   // [65536, 64]
  const float* e = (const float*)d_in[1];   // [1024, 64]
  float* out = (float*)d_out;               // quantized_st [65536*64] + loss [1]

  unsigned short* eB = (unsigned short*)d_ws;                 // 393216 B
  float* e2h     = (float*)((char*)d_ws + 64 * 6 * 512 * 2);  // 4 KB
  float* partial = e2h + NCODE;                               // 4 KB

  vq_esplit<<<NCODE / 256, 256, 0, stream>>>(e, eB, e2h);
  vq_main  <<<NBLK, 256, 0, stream>>>(x, e, eB, e2h, out, partial);
  vq_fin   <<<1, NBLK, 0, stream>>>(partial, out + (size_t)NROWS * DIM);
}

// Round 5
// 68.640 us; speedup vs baseline: 8.0417x; 1.0089x over previous
//
#include <hip/hip_runtime.h>

#define DIM   64
#define NROWS 65536
#define NCODE 1024
#define NBLK  (NROWS / 64)      // 1024 blocks, 64 rows each

typedef float    f32x4 __attribute__((ext_vector_type(4)));
typedef _Float16 f16x8 __attribute__((ext_vector_type(8)));

union U4H { uint4 u; f16x8 h; };

// fp32 = h + r, h = RNE fp16; r exact (Sterbenz); l = RNE fp16 of r.
// Residual |x-h-l| <= 2^-22|x|; dropped MFMA terms (ll, residuals) give
// distance error sd ~2e-7 << typical best-vs-2nd gap (~0.8, min ~1e-5).
__device__ __forceinline__ void split2(float f, unsigned short& hb,
                                       unsigned short& lb) {
  _Float16 h = (_Float16)f;
  float r = f - (float)h;
  _Float16 l = (_Float16)r;
  hb = __builtin_bit_cast(unsigned short, h);
  lb = __builtin_bit_cast(unsigned short, l);
}
__device__ __forceinline__ uint4 pack8(const unsigned short* p) {
  return make_uint4((unsigned)p[0] | ((unsigned)p[1] << 16),
                    (unsigned)p[2] | ((unsigned)p[3] << 16),
                    (unsigned)p[4] | ((unsigned)p[5] << 16),
                    (unsigned)p[6] | ((unsigned)p[7] << 16));
}

// ---- pre-pass: e -> fp16 (h,l) B-fragments + e2/2 ----
// tile gt (16 codes): 4 frags [kh0_h, kh0_l, kh1_h, kh1_l] x 512 shorts.
// Frag element (lane, i): code = gt*16 + (lane&15), k = kh*32 + (lane>>4)*8 + i
__global__ __launch_bounds__(256) void vq_esplit(const float* __restrict__ e,
                                                 unsigned short* __restrict__ eB,
                                                 float* __restrict__ e2h) {
  const int c = blockIdx.x * 256 + threadIdx.x;   // code 0..1023
  const int gt = c >> 4, cl = c & 15;
  float s = 0.f;
  #pragma unroll
  for (int kh = 0; kh < 2; ++kh) {
    #pragma unroll
    for (int g = 0; g < 4; ++g) {
      const float* ep = e + (size_t)c * DIM + kh * 32 + g * 8;
      float4 v0 = *(const float4*)ep;
      float4 v1 = *(const float4*)(ep + 4);
      float f[8] = {v0.x, v0.y, v0.z, v0.w, v1.x, v1.y, v1.z, v1.w};
      unsigned short hb[8], lb[8];
      #pragma unroll
      for (int j = 0; j < 8; ++j) {
        split2(f[j], hb[j], lb[j]);
        s = fmaf(f[j], f[j], s);
      }
      const size_t pos = (size_t)((g << 4) | cl) * 8;
      const size_t tb = (size_t)gt * 2048;
      *(uint4*)(eB + tb + (kh * 2 + 0) * 512 + pos) = pack8(hb);
      *(uint4*)(eB + tb + (kh * 2 + 1) * 512 + pos) = pack8(lb);
    }
  }
  e2h[c] = 0.5f * s;
}

// S' = dot(x,e) - e2/2 computed as one MFMA chain seeded with C = -e2/2.
#define VQ_STEP(CT, BUF, E2L)                                                      \
  {                                                                                \
    U4H u0, u1, u2, u3;                                                            \
    u0.u = BUF[0]; u1.u = BUF[1]; u2.u = BUF[2]; u3.u = BUF[3];                    \
    f16x8 b0h = u0.h, b0l = u1.h, b1h = u2.h, b1l = u3.h;                          \
    const int kk0 = w * 256 + (CT) * 16 + col;                                     \
    const float ne2 = -(E2L);                                                      \
    _Pragma("unroll")                                                              \
    for (int rt = 0; rt < 4; ++rt) {                                               \
      f32x4 c = {ne2, ne2, ne2, ne2};                                              \
      c = __builtin_amdgcn_mfma_f32_16x16x32_f16(a[rt][0][0], b0h, c, 0, 0, 0);    \
      c = __builtin_amdgcn_mfma_f32_16x16x32_f16(a[rt][0][1], b0h, c, 0, 0, 0);    \
      c = __builtin_amdgcn_mfma_f32_16x16x32_f16(a[rt][0][0], b0l, c, 0, 0, 0);    \
      c = __builtin_amdgcn_mfma_f32_16x16x32_f16(a[rt][1][0], b1h, c, 0, 0, 0);    \
      c = __builtin_amdgcn_mfma_f32_16x16x32_f16(a[rt][1][1], b1h, c, 0, 0, 0);    \
      c = __builtin_amdgcn_mfma_f32_16x16x32_f16(a[rt][1][0], b1l, c, 0, 0, 0);    \
      _Pragma("unroll")                                                            \
      for (int r = 0; r < 4; ++r) {                                                \
        if (c[r] > bestS[rt][r]) { bestS[rt][r] = c[r]; bestK[rt][r] = kk0; }      \
      }                                                                            \
    }                                                                              \
  }

// ---- main: 64 rows/block, 4 waves; wave w scans codes [w*256, w*256+256) ----
__global__ __launch_bounds__(256, 2) void vq_main(
    const float* __restrict__ x,
    const float* __restrict__ e,
    const unsigned short* __restrict__ eB,
    const float* __restrict__ e2h,
    float* __restrict__ out,
    float* __restrict__ loss)
{
  __shared__ float bestL[256];
  __shared__ int   kL[256];
  __shared__ int   kFin[64];
  __shared__ float x2s;

  const int t   = threadIdx.x;
  const int l   = t & 63;
  const int w   = t >> 6;
  const int col = l & 15;
  const int g   = l >> 4;
  const int B0  = blockIdx.x * 64;

  // ---- x -> fp16 (h,l) A-fragments in registers + Sum(x^2) ----
  f16x8 a[4][2][2];     // [row-tile][k-half][h/l]
  float x2p = 0.f;
  #pragma unroll
  for (int rt = 0; rt < 4; ++rt) {
    #pragma unroll
    for (int kh = 0; kh < 2; ++kh) {
      const float* xp = x + (size_t)(B0 + rt * 16 + col) * DIM + kh * 32 + g * 8;
      float4 v0 = *(const float4*)xp;
      float4 v1 = *(const float4*)(xp + 4);
      float f[8] = {v0.x, v0.y, v0.z, v0.w, v1.x, v1.y, v1.z, v1.w};
      unsigned short hb[8], lb[8];
      #pragma unroll
      for (int j = 0; j < 8; ++j) {
        split2(f[j], hb[j], lb[j]);
        x2p = fmaf(f[j], f[j], x2p);
      }
      U4H uh; uh.u = pack8(hb); a[rt][kh][0] = uh.h;
      U4H ul; ul.u = pack8(lb); a[rt][kh][1] = ul.h;
    }
  }
  // each wave covers all 64 rows x 64 dims exactly once -> full-wave reduce
  #pragma unroll
  for (int off = 1; off < 64; off <<= 1) x2p += __shfl_xor(x2p, off, 64);
  if (t == 0) x2s = x2p;

  float bestS[4][4];
  int   bestK[4][4];
  #pragma unroll
  for (int rt = 0; rt < 4; ++rt)
    #pragma unroll
    for (int r = 0; r < 4; ++r) { bestS[rt][r] = -3.402823466e38f; bestK[rt][r] = 0; }

  const unsigned short* ebase = eB + (size_t)w * 16 * 2048;
  const float* e2w = e2h + w * 256 + col;

  uint4 bA[4], bB[4];
  float e2A, e2B;
  #pragma unroll
  for (int q = 0; q < 4; ++q)
    bA[q] = *(const uint4*)(ebase + (size_t)q * 512 + l * 8);
  e2A = e2w[0];

  for (int ct = 0; ct < 16; ct += 2) {
    #pragma unroll
    for (int q = 0; q < 4; ++q)
      bB[q] = *(const uint4*)(ebase + (size_t)(ct + 1) * 2048 + (size_t)q * 512 + l * 8);
    e2B = e2w[(ct + 1) * 16];
    VQ_STEP(ct, bA, e2A);
    const int ctn = (ct + 2 < 16) ? ct + 2 : 14;   // tail reload, harmless
    #pragma unroll
    for (int q = 0; q < 4; ++q)
      bA[q] = *(const uint4*)(ebase + (size_t)ctn * 2048 + (size_t)q * 512 + l * 8);
    e2A = e2w[ctn * 16];
    VQ_STEP(ct + 1, bB, e2B);
  }

  // ---- intra-wave argmax(S') merge over the 16 code-columns ----
  #pragma unroll
  for (int off = 1; off <= 8; off <<= 1) {
    #pragma unroll
    for (int rt = 0; rt < 4; ++rt)
      #pragma unroll
      for (int r = 0; r < 4; ++r) {
        float sp = __shfl_xor(bestS[rt][r], off, 64);
        int   kp = __shfl_xor(bestK[rt][r], off, 64);
        if (sp > bestS[rt][r] || (sp == bestS[rt][r] && kp < bestK[rt][r])) {
          bestS[rt][r] = sp; bestK[rt][r] = kp;
        }
      }
  }
  if (col == 0) {
    #pragma unroll
    for (int rt = 0; rt < 4; ++rt)
      #pragma unroll
      for (int r = 0; r < 4; ++r) {
        const int row = rt * 16 + g * 4 + r;
        bestL[w * 64 + row] = bestS[rt][r];
        kL[w * 64 + row]    = bestK[rt][r];
      }
  }
  __syncthreads();

  // ---- cross-wave merge (ascending code ranges; strict > keeps lowest k) ----
  if (t < 64) {
    float s = bestL[t]; int k = kL[t];
    #pragma unroll
    for (int w2 = 1; w2 < 4; ++w2) {
      float s2 = bestL[w2 * 64 + t]; int k2 = kL[w2 * 64 + t];
      if (s2 > s) { s = s2; k = k2; }
    }
    kFin[t] = k;
    float rs = s;
    #pragma unroll
    for (int off = 1; off < 64; off <<= 1) rs += __shfl_xor(rs, off, 64);
    if (t == 0)   // sum_d(block) = x2 - 2*Sum(S'best); scale then one atomic
      atomicAdd(loss, fmaf(-2.f, rs, x2s) * (1.25f / (float)((size_t)NROWS * DIM)));
  }
  __syncthreads();

  // ---- cooperative gather-write of quantized rows (exact fp32 e copy) ----
  {
    const int row = t >> 2, seg = t & 3;
    const int bk = kFin[row];
    const float4* src = (const float4*)(e + (size_t)bk * DIM + seg * 16);
    float4* dst = (float4*)(out + (size_t)(B0 + row) * DIM + seg * 16);
    #pragma unroll
    for (int i = 0; i < 4; ++i) dst[i] = src[i];
  }
}

extern "C" void kernel_launch(void* const* d_in, const int* in_sizes, int n_in,
                              void* d_out, int out_size, void* d_ws, size_t ws_size,
                              hipStream_t stream) {
  const float* x = (const float*)d_in[0];   // [65536, 64]
  const float* e = (const float*)d_in[1];   // [1024, 64]
  float* out  = (float*)d_out;              // quantized_st [65536*64] + loss [1]
  float* loss = out + (size_t)NROWS * DIM;

  unsigned short* eB = (unsigned short*)d_ws;            // 64 tiles * 2048 shorts = 256 KB
  float* e2h = (float*)((char*)d_ws + 64 * 2048 * 2);    // 4 KB

  hipMemsetAsync(loss, 0, sizeof(float), stream);
  vq_esplit<<<NCODE / 256, 256, 0, stream>>>(e, eB, e2h);
  vq_main  <<<NBLK, 256, 0, stream>>>(x, e, eB, e2h, out, loss);
}